// Round 2
// baseline (714.607 us; speedup 1.0000x reference)
//
#include <hip/hip_runtime.h>

#define EPSF 0.01f
#define THREADS 256
#define ITEMS 32
#define TILE (THREADS * ITEMS)  // 8192 elements per block

typedef unsigned long long u64;

// Per-category change scalars, exactly as the reference computes them.
// jnp.clip(x, lo, hi) == min(max(x, lo), hi)
__device__ __forceinline__ void load_changes(const float* bd, const float* de,
                                             const float* sa, const float* in,
                                             const float* bi, float ch[5]) {
    float vbd = *bd, vd = *de, vs = *sa, vi = *in, vbi = *bi;
    ch[0] = fminf(vbd, fminf(0.0f, vd) - EPSF);
    ch[1] = fminf(fmaxf(vd, vbd + EPSF), 0.0f - EPSF);
    ch[2] = fminf(fmaxf(vs, vd + EPSF), vi - EPSF);
    ch[3] = fminf(fmaxf(vi, 0.0f + EPSF), vbi - EPSF);
    ch[4] = fmaxf(vbi, fmaxf(0.0f, vi) + EPSF);
}

__device__ __forceinline__ float sel_change(int v, float c0, float c1, float c2,
                                            float c3, float c4) {
    // cmp+cndmask chain; no runtime-indexed array (scratch), no LDS table.
    return (v == 1) ? c0 : (v == 2) ? c1 : (v == 3) ? c2 : (v == 4) ? c3 : c4;
}

__device__ __forceinline__ u64 pack_state(float v, int flag) {
    return ((u64)__float_as_uint(v) << 32) | (u64)flag;
}

// Clear lookback state + ticket counter every launch (d_ws is poisoned once
// to 0xAA and never re-poisoned; stale PREFIX flags would corrupt replays).
__global__ void k_init(u64* __restrict__ st, int words) {
    int i = blockIdx.x * blockDim.x + threadIdx.x;
    if (i < words) st[i] = 0ull;
}

// Single-pass scan with decoupled lookback.
// flag: 0 = invalid, 1 = aggregate published, 2 = inclusive prefix published.
// Ticket-based virtual block ids: a spinning block only waits on blocks that
// STARTED earlier (smaller ticket) -> resident & non-preemptible -> no deadlock,
// regardless of HW dispatch order.
__global__ __launch_bounds__(THREADS) void k_scan1(
    const int* __restrict__ ann, float* __restrict__ out, long long n, int nb,
    u64* __restrict__ state, int* __restrict__ counter, const float* org,
    const float* bd, const float* de, const float* sa, const float* in,
    const float* bi) {
    __shared__ int s_vbid;
    __shared__ float s_excl;
    __shared__ float wsum[THREADS / 64];

    if (threadIdx.x == 0) s_vbid = atomicAdd(counter, 1);  // device-scope
    float ch[5];
    load_changes(bd, de, sa, in, bi, ch);
    const float c0 = ch[0], c1 = ch[1], c2 = ch[2], c3 = ch[3], c4 = ch[4];
    __syncthreads();
    const int vbid = s_vbid;
    const long long tstart = (long long)vbid * TILE;
    const long long i0 = tstart + (long long)threadIdx.x * ITEMS;
    const int lane = threadIdx.x & 63, wv = threadIdx.x >> 6;

    // Per-thread 32-element EXCLUSIVE prefix in registers (all indices static).
    float e[ITEMS + 1];
    e[0] = 0.0f;
    const bool full = (tstart + TILE <= n);
    if (full) {
        const int4* p = reinterpret_cast<const int4*>(ann + i0);
#pragma unroll
        for (int k = 0; k < ITEMS / 4; ++k) {
            int4 a = p[k];
            e[4 * k + 1] = e[4 * k + 0] + sel_change(a.x, c0, c1, c2, c3, c4);
            e[4 * k + 2] = e[4 * k + 1] + sel_change(a.y, c0, c1, c2, c3, c4);
            e[4 * k + 3] = e[4 * k + 2] + sel_change(a.z, c0, c1, c2, c3, c4);
            e[4 * k + 4] = e[4 * k + 3] + sel_change(a.w, c0, c1, c2, c3, c4);
        }
    } else {
#pragma unroll
        for (int j = 0; j < ITEMS; ++j) {
            float cv = 0.0f;
            if (i0 + j < n) cv = sel_change(ann[i0 + j], c0, c1, c2, c3, c4);
            e[j + 1] = e[j] + cv;
        }
    }
    float lsum = e[ITEMS];

    // Block scan of per-thread sums: wave inclusive scan + wave totals in LDS.
    float x = lsum;
#pragma unroll
    for (int off = 1; off < 64; off <<= 1) {
        float y = __shfl_up(x, off, 64);
        if (lane >= off) x += y;
    }
    if (lane == 63) wsum[wv] = x;
    __syncthreads();
    float w0 = wsum[0], w1 = wsum[1], w2 = wsum[2], w3 = wsum[3];
    float waveOff =
        (wv > 0 ? w0 : 0.0f) + (wv > 1 ? w1 : 0.0f) + (wv > 2 ? w2 : 0.0f);
    float agg = w0 + w1 + w2 + w3;  // block aggregate

    // Wave 0: publish aggregate, lookback for exclusive prefix, publish prefix.
    if (wv == 0) {
        float excl;
        if (vbid == 0) {
            excl = *org;  // prefix chain carries origin
            if (lane == 0)
                __hip_atomic_store(&state[0], pack_state(excl + agg, 2),
                                   __ATOMIC_RELEASE, __HIP_MEMORY_SCOPE_AGENT);
        } else {
            if (lane == 0)
                __hip_atomic_store(&state[vbid], pack_state(agg, 1),
                                   __ATOMIC_RELEASE, __HIP_MEMORY_SCOPE_AGENT);
            excl = 0.0f;
            int i = vbid - 1;
            for (;;) {
                int idx = i - lane;  // lane 0 = nearest predecessor
                bool active = (idx >= 0);
                u64 w = 0;
                int flag;
                do {
                    flag = 1;
                    if (active) {
                        w = __hip_atomic_load(&state[idx], __ATOMIC_ACQUIRE,
                                              __HIP_MEMORY_SCOPE_AGENT);
                        flag = (int)(w & 3ull);
                        if (flag == 0) __builtin_amdgcn_s_sleep(1);
                    }
                } while (__any(flag == 0));
                float val = active ? __uint_as_float((unsigned)(w >> 32)) : 0.0f;
                u64 pmask = __ballot(active && flag == 2);
                float contrib;
                bool done;
                if (pmask) {
                    // nearest PREFIX: smallest set lane; closer lanes are all AGG
                    int L = __ffsll(pmask) - 1;
                    contrib = (lane <= L) ? val : 0.0f;
                    done = true;
                } else {
                    contrib = val;  // 64 aggregates, keep walking
                    done = false;
                }
#pragma unroll
                for (int off = 1; off < 64; off <<= 1)
                    contrib += __shfl_xor(contrib, off, 64);
                excl += contrib;
                if (done) break;
                i -= 64;
            }
            if (lane == 0)
                __hip_atomic_store(&state[vbid], pack_state(excl + agg, 2),
                                   __ATOMIC_RELEASE, __HIP_MEMORY_SCOPE_AGENT);
        }
        if (lane == 0) s_excl = excl;
    }
    __syncthreads();
    const float excl = s_excl;

    // Emit: out[o] = exclusive_prefix(o), all float4 stores 16B-aligned.
    float base = excl + waveOff + (x - lsum);
    if (full) {
        float4* q = reinterpret_cast<float4*>(out + i0);
#pragma unroll
        for (int k = 0; k < ITEMS / 4; ++k)
            q[k] = make_float4(base + e[4 * k + 0], base + e[4 * k + 1],
                               base + e[4 * k + 2], base + e[4 * k + 3]);
    } else {
#pragma unroll
        for (int j = 0; j < ITEMS; ++j)
            if (i0 + j < n) out[i0 + j] = base + e[j];
    }
    if (vbid == nb - 1 && threadIdx.x == 0) out[n] = excl + agg;
}

extern "C" void kernel_launch(void* const* d_in, const int* in_sizes, int n_in,
                              void* d_out, int out_size, void* d_ws, size_t ws_size,
                              hipStream_t stream) {
    const int* ann = (const int*)d_in[0];
    const float* org = (const float*)d_in[1];
    const float* bd = (const float*)d_in[2];
    const float* de = (const float*)d_in[3];
    const float* sa = (const float*)d_in[4];
    const float* in = (const float*)d_in[5];
    const float* bi = (const float*)d_in[6];
    float* out = (float*)d_out;

    long long n = (long long)in_sizes[0];
    int nb = (int)((n + TILE - 1) / TILE);
    if (nb < 1) nb = 1;

    u64* state = (u64*)d_ws;            // nb packed {f32,flag} words
    int* counter = (int*)(state + nb);  // ticket counter (one u64 slot)
    int words = nb + 1;

    k_init<<<(words + 255) / 256, 256, 0, stream>>>(state, words);
    k_scan1<<<nb, THREADS, 0, stream>>>(ann, out, n, nb, state, counter, org,
                                        bd, de, sa, in, bi);
}

// Round 3
// 89.594 us; speedup vs baseline: 7.9761x; 7.9761x over previous
//
#include <hip/hip_runtime.h>

#define EPSF 0.01f
#define THREADS 256
#define ITEMS 16
#define TILE (THREADS * ITEMS)  // 4096 elements per emit tile
#define NB 2048                 // target block count (8 blocks/CU)

typedef unsigned long long u64;

// Per-category change scalars, exactly as the reference computes them.
// jnp.clip(x, lo, hi) == min(max(x, lo), hi)
__device__ __forceinline__ void load_changes(const float* bd, const float* de,
                                             const float* sa, const float* in,
                                             const float* bi, float ch[5]) {
    float vbd = *bd, vd = *de, vs = *sa, vi = *in, vbi = *bi;
    ch[0] = fminf(vbd, fminf(0.0f, vd) - EPSF);
    ch[1] = fminf(fmaxf(vd, vbd + EPSF), 0.0f - EPSF);
    ch[2] = fminf(fmaxf(vs, vd + EPSF), vi - EPSF);
    ch[3] = fminf(fmaxf(vi, 0.0f + EPSF), vbi - EPSF);
    ch[4] = fmaxf(vbi, fmaxf(0.0f, vi) + EPSF);
}

__device__ __forceinline__ float sel_change(int v, float c0, float c1, float c2,
                                            float c3, float c4) {
    // cmp+cndmask chain; no runtime-indexed array (scratch), no LDS table.
    return (v == 1) ? c0 : (v == 2) ? c1 : (v == 3) ? c2 : (v == 4) ? c3 : c4;
}

// Pass 1: exact per-block category counts (packed 12-bit fields; per-thread
// count = chunk/256 = 64 << 4095). Counts stored TRANSPOSED: bcT[c*nb + b]
// so pass 2's predecessor-sum is coalesced per category.
__global__ __launch_bounds__(THREADS) void k_count(const int* __restrict__ ann,
                                                   int* __restrict__ bcT,
                                                   long long n, long long chunk,
                                                   int nb) {
    long long start = (long long)blockIdx.x * chunk;
    long long end = start + chunk;
    if (end > n) end = n;

    u64 pk = 0ull;
    long long i = start + (long long)threadIdx.x * 4;
    const long long stride = (long long)blockDim.x * 4;
    for (; i + 3 < end; i += stride) {
        int4 a = *reinterpret_cast<const int4*>(ann + i);
        pk += (1ull << ((a.x - 1) * 12));
        pk += (1ull << ((a.y - 1) * 12));
        pk += (1ull << ((a.z - 1) * 12));
        pk += (1ull << ((a.w - 1) * 12));
    }
    if (i < end) {  // at most one thread lands here; <=3 scalar elems
        for (long long j = i; j < end; ++j) pk += (1ull << ((ann[j] - 1) * 12));
    }

    int cnt[5];
#pragma unroll
    for (int c = 0; c < 5; ++c) cnt[c] = (int)((pk >> (c * 12)) & 0xFFFull);

    int lane = threadIdx.x & 63, wv = threadIdx.x >> 6;
#pragma unroll
    for (int c = 0; c < 5; ++c) {
        int x = cnt[c];
#pragma unroll
        for (int off = 32; off > 0; off >>= 1) x += __shfl_down(x, off, 64);
        cnt[c] = x;  // lane 0 holds wave total
    }
    __shared__ int sred[THREADS / 64][5];
    if (lane == 0) {
#pragma unroll
        for (int c = 0; c < 5; ++c) sred[wv][c] = cnt[c];
    }
    __syncthreads();
    if (threadIdx.x == 0) {
#pragma unroll
        for (int c = 0; c < 5; ++c)
            bcT[c * nb + blockIdx.x] =
                sred[0][c] + sred[1][c] + sred[2][c] + sred[3][c];
    }
}

// Pass 2: each block redundantly sums its predecessors' counts (40 KB array,
// L2-resident -> no serialization, no extra kernel), derives its exact float
// base, then gathers + scans + emits its chunk. Exclusive-prefix form keeps
// every float4 store 16B-aligned and makes out[0]=origin fall out naturally.
__global__ __launch_bounds__(THREADS) void k_emit(
    const int* __restrict__ ann, const int* __restrict__ bcT,
    float* __restrict__ out, long long n, long long chunk, int nb,
    const float* org, const float* bd, const float* de, const float* sa,
    const float* in, const float* bi) {
    float ch[5];
    load_changes(bd, de, sa, in, bi, ch);
    const float c0 = ch[0], c1 = ch[1], c2 = ch[2], c3 = ch[3], c4 = ch[4];

    __shared__ int sred[THREADS / 64][5];
    __shared__ float wsum[THREADS / 64];
    __shared__ float s_base;

    const int vbid = blockIdx.x;
    const int lane = threadIdx.x & 63, wv = threadIdx.x >> 6;

    // --- Phase A: exclusive base = org + sum_c (#cat_c before my chunk)*ch_c
    int pc[5];
#pragma unroll
    for (int c = 0; c < 5; ++c) {
        int s = 0;
        for (int j = threadIdx.x; j < vbid; j += THREADS) s += bcT[c * nb + j];
#pragma unroll
        for (int off = 32; off > 0; off >>= 1) s += __shfl_down(s, off, 64);
        pc[c] = s;
    }
    if (lane == 0) {
#pragma unroll
        for (int c = 0; c < 5; ++c) sred[wv][c] = pc[c];
    }
    __syncthreads();
    if (threadIdx.x == 0) {
        double acc = (double)(*org);
#pragma unroll
        for (int c = 0; c < 5; ++c) {
            int tot = sred[0][c] + sred[1][c] + sred[2][c] + sred[3][c];
            acc += (double)tot * (double)ch[c];
        }
        s_base = (float)acc;
    }
    __syncthreads();

    // --- Phase B: gather + block scan + emit
    long long start = (long long)vbid * chunk;
    long long end = start + chunk;
    if (end > n) end = n;
    float running = s_base;

    for (long long ts = start; ts < end; ts += TILE) {
        long long i0 = ts + (long long)threadIdx.x * ITEMS;
        float e[ITEMS + 1];
        e[0] = 0.0f;
        const bool full = (ts + TILE <= n);
        if (full) {
            const int4* p = reinterpret_cast<const int4*>(ann + i0);
#pragma unroll
            for (int k = 0; k < ITEMS / 4; ++k) {
                int4 a = p[k];
                e[4 * k + 1] = e[4 * k + 0] + sel_change(a.x, c0, c1, c2, c3, c4);
                e[4 * k + 2] = e[4 * k + 1] + sel_change(a.y, c0, c1, c2, c3, c4);
                e[4 * k + 3] = e[4 * k + 2] + sel_change(a.z, c0, c1, c2, c3, c4);
                e[4 * k + 4] = e[4 * k + 3] + sel_change(a.w, c0, c1, c2, c3, c4);
            }
        } else {
#pragma unroll
            for (int j = 0; j < ITEMS; ++j) {
                float cv = 0.0f;
                if (i0 + j < n) cv = sel_change(ann[i0 + j], c0, c1, c2, c3, c4);
                e[j + 1] = e[j] + cv;
            }
        }
        float lsum = e[ITEMS];

        // block exclusive scan of per-thread sums
        float x = lsum;
#pragma unroll
        for (int off = 1; off < 64; off <<= 1) {
            float y = __shfl_up(x, off, 64);
            if (lane >= off) x += y;
        }
        if (lane == 63) wsum[wv] = x;
        __syncthreads();
        float w0 = wsum[0], w1 = wsum[1], w2 = wsum[2], w3 = wsum[3];
        float waveOff = (wv > 0 ? w0 : 0.0f) + (wv > 1 ? w1 : 0.0f) +
                        (wv > 2 ? w2 : 0.0f);
        float total = w0 + w1 + w2 + w3;
        __syncthreads();  // wsum reusable next tile

        float base = running + waveOff + (x - lsum);
        if (full) {
            float4* q = reinterpret_cast<float4*>(out + i0);
#pragma unroll
            for (int k = 0; k < ITEMS / 4; ++k)
                q[k] = make_float4(base + e[4 * k + 0], base + e[4 * k + 1],
                                   base + e[4 * k + 2], base + e[4 * k + 3]);
        } else {
#pragma unroll
            for (int j = 0; j < ITEMS; ++j)
                if (i0 + j < n) out[i0 + j] = base + e[j];
        }
        running += total;
    }
    if (end == n && start < n && threadIdx.x == 0) out[n] = running;
}

extern "C" void kernel_launch(void* const* d_in, const int* in_sizes, int n_in,
                              void* d_out, int out_size, void* d_ws, size_t ws_size,
                              hipStream_t stream) {
    const int* ann = (const int*)d_in[0];
    const float* org = (const float*)d_in[1];
    const float* bd = (const float*)d_in[2];
    const float* de = (const float*)d_in[3];
    const float* sa = (const float*)d_in[4];
    const float* in = (const float*)d_in[5];
    const float* bi = (const float*)d_in[6];
    float* out = (float*)d_out;

    long long n = (long long)in_sizes[0];
    long long nTiles = (n + TILE - 1) / TILE;
    long long tpb = (nTiles + NB - 1) / NB;  // tiles per block
    if (tpb < 1) tpb = 1;
    long long chunk = tpb * TILE;            // 16384 for N=2^25
    int nb = (int)((n + chunk - 1) / chunk); // 2048 for N=2^25
    if (nb < 1) nb = 1;

    int* bcT = (int*)d_ws;  // nb*5 ints, transposed [c][b]

    k_count<<<nb, THREADS, 0, stream>>>(ann, bcT, n, chunk, nb);
    k_emit<<<nb, THREADS, 0, stream>>>(ann, bcT, out, n, chunk, nb, org, bd, de,
                                       sa, in, bi);
}